// Round 5
// baseline (314.608 us; speedup 1.0000x reference)
//
#include <hip/hip_runtime.h>
#include <stdint.h>

typedef unsigned short u16;
typedef unsigned int u32;
typedef __bf16 bf16x8 __attribute__((ext_vector_type(8)));
typedef __bf16 bf16x4 __attribute__((ext_vector_type(4)));
typedef float f32x4 __attribute__((ext_vector_type(4)));
typedef float f32x16 __attribute__((ext_vector_type(16)));
typedef u32 u32x4 __attribute__((ext_vector_type(4)));

#define SEQ 2048
#define QSCALE 0.1803368801111137f  // log2(e)/8, folded into W_q_eff

__device__ __forceinline__ float fast_exp2(float x) { return __builtin_amdgcn_exp2f(x); }

// async 16B global->LDS copy (wave-uniform LDS base + lane*16)
__device__ __forceinline__ void async16(const void* g, void* l) {
  __builtin_amdgcn_global_load_lds((const __attribute__((address_space(1))) void*)g,
                                   (__attribute__((address_space(3))) void*)l, 16, 0, 0);
}

__device__ __forceinline__ u32 pkbf(float a, float b) {
  u16 xa = __builtin_bit_cast(u16, (__bf16)a);
  u16 xb = __builtin_bit_cast(u16, (__bf16)b);
  return (u32)xa | ((u32)xb << 16);
}

// ---------------- fused prep kernel ----------------
// blocks [0,8192): x fp32->bf16; [8192,12288): W_eff^T build; [12288,12300): bias.

__global__ void prep_all_kernel(const float* __restrict__ x, u16* __restrict__ xb,
                                const float* __restrict__ wq, const float* __restrict__ wk,
                                const float* __restrict__ wv, const float* __restrict__ wo,
                                const float* __restrict__ aq, const float* __restrict__ ak,
                                const float* __restrict__ av,
                                const float* __restrict__ uq, const float* __restrict__ uk,
                                const float* __restrict__ uv,
                                u16* __restrict__ weffT,
                                const float* __restrict__ bq, const float* __restrict__ bk,
                                const float* __restrict__ bv, float* __restrict__ bias_qkv) {
  __shared__ float wt[32][33];
  __shared__ float at[32][8];
  __shared__ float ut[8][33];
  const int bid = blockIdx.x;
  const int t = threadIdx.x;
  if (bid < 8192) {
    int i = (bid * 256 + t) * 4;
    float4 v = *(const float4*)(x + i);
    bf16x4 o;
    o[0] = (__bf16)v.x; o[1] = (__bf16)v.y; o[2] = (__bf16)v.z; o[3] = (__bf16)v.w;
    *(bf16x4*)(xb + i) = o;
  } else if (bid < 12288) {
    const int p = (bid - 8192) >> 10, bx = (bid - 8192) & 1023;
    const int tn0 = (bx & 31) * 32, tk0 = (bx >> 5) * 32;
    const float* w = (p == 0) ? wq : (p == 1) ? wk : (p == 2) ? wv : wo;
    const float* a = (p == 0) ? aq : (p == 1) ? ak : av;
    const float* u = (p == 0) ? uq : (p == 1) ? uk : uv;
    {
      int tk = t >> 3, tn4 = (t & 7) * 4;
      float4 v = *(const float4*)(w + (tk0 + tk) * 1024 + tn0 + tn4);
      wt[tk][tn4] = v.x; wt[tk][tn4 + 1] = v.y; wt[tk][tn4 + 2] = v.z; wt[tk][tn4 + 3] = v.w;
    }
    if (p < 3) {
      at[t >> 3][t & 7] = a[(tk0 + (t >> 3)) * 8 + (t & 7)];
      ut[t >> 5][t & 31] = u[(t >> 5) * 1024 + tn0 + (t & 31)];
    }
    __syncthreads();
    const int tn = t >> 3, tk4 = (t & 7) * 4;
    bf16x4 o;
#pragma unroll
    for (int jj = 0; jj < 4; ++jj) {
      int k = tk4 + jj;
      float val = wt[k][tn];
      if (p < 3) {
        float acc = 0.f;
#pragma unroll
        for (int r = 0; r < 8; ++r) acc += at[k][r] * ut[r][tn];
        val += 2.0f * acc;
      }
      if (p == 0) val *= QSCALE;
      o[jj] = (__bf16)val;
    }
    *(bf16x4*)(weffT + p * 1048576 + (tn0 + tn) * 1024 + tk0 + tk4) = o;
  } else {
    int i = (bid - 12288) * 256 + t;
    bias_qkv[i] = (i < 1024) ? bq[i] * QSCALE : (i < 2048) ? bk[i - 1024] : bv[i - 2048];
  }
}

// ---------------- GEMM: OUT[v][u] = dot(U[u], V[v]) + bias[u] ----------------
// Block 128(u) x 128(v), BK=32, 4 waves 2x2, wave tile 64x64 (4x4 MFMAs).
// MODE 0: fp32 dense store (stride NU). MODE 1: u<2048 -> bf16 qkv (stride 2048);
//         u>=2048 -> V^T scatter into vT[b][h][d][s] (L2 merges to full lines).

template <int MODE>
__global__ __launch_bounds__(256, 2)
void gemm_tt(const u16* __restrict__ U, const u16* __restrict__ V, void* __restrict__ OUT,
             u16* __restrict__ vT, const float* __restrict__ bias, const int NU, const int K) {
  __shared__ __align__(16) char smU[8192];
  __shared__ __align__(16) char smV[8192];
  const int t = threadIdx.x;
  const int lane = t & 63, ln = lane & 15, g = lane >> 4, w = t >> 6;
  const int u0 = blockIdx.x * 128, v0 = blockIdx.y * 128;
  const int wu = (w & 1) * 64, wv = (w >> 1) * 64;
  f32x4 acc[4][4] = {};
  for (int k0 = 0; k0 < K; k0 += 32) {
    __syncthreads();
#pragma unroll
    for (int half = 0; half < 2; ++half) {
      int p = half * 256 + t;
      int s = p >> 2, cp = p & 3;
      int c = cp ^ (s & 3);
      int ldsoff = (half * 256 + (t & 192)) * 16;
      async16(U + (u0 + s) * K + k0 + c * 8, smU + ldsoff);
      async16(V + (v0 + s) * K + k0 + c * 8, smV + ldsoff);
    }
    __syncthreads();
    bf16x8 af[4], bf[4];
#pragma unroll
    for (int mt = 0; mt < 4; ++mt)
      af[mt] = *(const bf16x8*)(smU + (wu + mt * 16 + ln) * 64 + ((g ^ (ln & 3)) * 16));
#pragma unroll
    for (int nt = 0; nt < 4; ++nt)
      bf[nt] = *(const bf16x8*)(smV + (wv + nt * 16 + ln) * 64 + ((g ^ (ln & 3)) * 16));
#pragma unroll
    for (int mt = 0; mt < 4; ++mt)
#pragma unroll
      for (int nt = 0; nt < 4; ++nt)
        acc[mt][nt] = __builtin_amdgcn_mfma_f32_16x16x32_bf16(af[mt], bf[nt], acc[mt][nt], 0, 0, 0);
  }
  const bool isV = (MODE == 1) && (u0 + wu >= 2048);  // wave-uniform
#pragma unroll
  for (int mt = 0; mt < 4; ++mt) {
    const int u = u0 + wu + mt * 16 + g * 4;
    const float4 bs = *(const float4*)(bias + u);
#pragma unroll
    for (int nt = 0; nt < 4; ++nt) {
      const int v = v0 + wv + nt * 16 + ln;
      f32x4 a = acc[mt][nt];
      a[0] += bs.x; a[1] += bs.y; a[2] += bs.z; a[3] += bs.w;
      if (MODE == 0) {
        *(float4*)((float*)OUT + (size_t)v * NU + u) = make_float4(a[0], a[1], a[2], a[3]);
      } else if (!isV) {
        bf16x4 o;
        o[0] = (__bf16)a[0]; o[1] = (__bf16)a[1]; o[2] = (__bf16)a[2]; o[3] = (__bf16)a[3];
        *(bf16x4*)((u16*)OUT + (size_t)v * 2048 + u) = o;
      } else {
        const int uu = u - 2048;
        const int hh = uu >> 6, dd = uu & 63;
        const int bb = v >> 11, ss = v & 2047;
        u16* dst = vT + ((size_t)((bb * 16 + hh) * 64 + dd)) * 2048 + ss;
#pragma unroll
        for (int r = 0; r < 4; ++r)
          *(__bf16*)(dst + (size_t)r * 2048) = (__bf16)a[r];
      }
    }
  }
}

// ---------------- flash attention v5 ----------------
// Block = (h, qt, b), 128 q, 4 waves x 32 q. 32x32x16 MFMAs. Q frags in regs.
// Fixed-max softmax: P = exp2(raw S) (log2e/8 folded into W_q).
// KEY TRICK: K rows staged into smK with row-index bits 2<->3 swapped, so the
// S^T MFMA C-output (reg r, half h) holds s' = 16*(r>>3) + 8h + (r&7) — exactly
// the B-operand fragment order for PV. P->B transpose costs ZERO instructions.
// l computed on the MFMA pipe via a constant ones A-fragment (row 0 = 1).
// smK  [128 rows][128B, 8 chunks, swz ^(r&7)]         (async16, row-permuted)
// smVt [64 d][256B, 16 chunks, swz ^((d&15)^(d>>3))]  (async16 from global vT)

__global__ __launch_bounds__(256, 3)
void attn_kernel(const u16* __restrict__ qkv, const u16* __restrict__ vT,
                 u16* __restrict__ attn_o) {
  __shared__ __align__(16) char smK[16384];
  __shared__ __align__(16) char smVt[16384];
  const int t = threadIdx.x;
  const int lane = t & 63, q32 = lane & 31, hf = lane >> 5, w = t >> 6;
  const int hd = blockIdx.x, qt = blockIdx.y, b = blockIdx.z;
  const int q0 = qt * 128;
  const size_t base_b = (size_t)b * SEQ * 2048;
  const u16* qbase = qkv + base_b + hd * 64;
  const u16* kbase0 = qkv + base_b + 1024 + hd * 64;
  const u16* vbase0 = vT + ((size_t)(b * 16 + hd) * 64) * 2048;

  // Q B-frags (32x32x16): lane(n=q32, kgroup=hf), k = ks*16 + hf*8 + j
  bf16x8 qf[4];
#pragma unroll
  for (int ks = 0; ks < 4; ++ks)
    qf[ks] = *(const bf16x8*)(qbase + (size_t)(q0 + w * 32 + q32) * 2048 + ks * 16 + hf * 8);

  // ones A-fragment: tile row m=0 holds 1.0 across all k -> C row 0 = column sums
  bf16x8 ones_frag;
  {
    u32 o2 = (q32 == 0) ? 0x3F803F80u : 0u;
    u32x4 ow = {o2, o2, o2, o2};
    ones_frag = __builtin_bit_cast(bf16x8, ow);
  }

  // staging address precompute (swizzled global source chunks)
  const u16* srcK[4];
  const u16* srcV[4];
  char* dstK[4];
  char* dstV[4];
#pragma unroll
  for (int i = 0; i < 4; ++i) {
    int p = i * 256 + t;
    {
      int row = p >> 3, cp = p & 7;
      int rowp = (row & ~12) | ((row & 4) << 1) | ((row & 8) >> 1);  // swap bits 2,3
      int c = cp ^ (row & 7);
      srcK[i] = kbase0 + (size_t)rowp * 2048 + c * 8;
      dstK[i] = smK + (i * 256 + (t & 192)) * 16;
    }
    {
      int d = p >> 4, cp = p & 15;
      int key = (d & 15) ^ (d >> 3);
      int c = (cp ^ key) & 15;
      srcV[i] = vbase0 + (size_t)d * 2048 + c * 8;
      dstV[i] = smVt + (i * 256 + (t & 192)) * 16;
    }
  }

  f32x16 accO[2] = {};
  f32x16 acc_l = {};

  for (int kt = 0; kt < 16; ++kt) {
    __syncthreads();  // prev iter done with smK/smVt
#pragma unroll
    for (int i = 0; i < 4; ++i) {
      async16(srcK[i], dstK[i]);
      srcK[i] += 128 * 2048;
    }
#pragma unroll
    for (int i = 0; i < 4; ++i) {
      async16(srcV[i], dstV[i]);
      srcV[i] += 128;
    }
    __syncthreads();

    // S^T = K @ Q^T : 4 m-chunks of 32 s'(permuted rows), n = wave's 32 q
    f32x16 st[4] = {};
#pragma unroll
    for (int ks = 0; ks < 4; ++ks) {
#pragma unroll
      for (int c = 0; c < 4; ++c) {
        int row = c * 32 + q32;
        bf16x8 kfr = *(const bf16x8*)(smK + row * 128 + (((2 * ks + hf) ^ (row & 7)) * 16));
        st[c] = __builtin_amdgcn_mfma_f32_32x32x16_bf16(kfr, qf[ks], st[c], 0, 0, 0);
      }
    }

    // per (c, kh): exp2 -> pack (already B-operand order) -> l-MFMA + PV MFMAs
#pragma unroll
    for (int c = 0; c < 4; ++c) {
#pragma unroll
      for (int kh = 0; kh < 2; ++kh) {
        float e[8];
#pragma unroll
        for (int j = 0; j < 8; ++j) e[j] = fast_exp2(st[c][8 * kh + j]);
        u32x4 bw;
        bw[0] = pkbf(e[0], e[1]);
        bw[1] = pkbf(e[2], e[3]);
        bw[2] = pkbf(e[4], e[5]);
        bw[3] = pkbf(e[6], e[7]);
        bf16x8 pfrag = __builtin_bit_cast(bf16x8, bw);
        acc_l = __builtin_amdgcn_mfma_f32_32x32x16_bf16(ones_frag, pfrag, acc_l, 0, 0, 0);
#pragma unroll
        for (int mt = 0; mt < 2; ++mt) {
          int row = mt * 32 + q32;
          int key = (row & 15) ^ (row >> 3);
          bf16x8 vfr = *(const bf16x8*)(smVt + row * 256 +
                                        (((4 * c + 2 * kh + hf) ^ key) & 15) * 16);
          accO[mt] = __builtin_amdgcn_mfma_f32_32x32x16_bf16(vfr, pfrag, accO[mt], 0, 0, 0);
        }
      }
    }
  }

  // l[q] lives in acc_l reg 0, half-0 lane q; broadcast to both halves
  float lv = __shfl(acc_l[0], q32);
  float il = 1.0f / lv;
  const int s = q0 + w * 32 + q32;
#pragma unroll
  for (int mt = 0; mt < 2; ++mt)
#pragma unroll
    for (int qd = 0; qd < 4; ++qd) {
      int d0 = 32 * mt + 8 * qd + 4 * hf;
      bf16x4 o;
#pragma unroll
      for (int r = 0; r < 4; ++r) o[r] = (__bf16)(accO[mt][4 * qd + r] * il);
      *(bf16x4*)(attn_o + (size_t)(b * SEQ + s) * 1024 + hd * 64 + d0) = o;
    }
}

// ---------------- launcher ----------------

extern "C" void kernel_launch(void* const* d_in, const int* in_sizes, int n_in,
                              void* d_out, int out_size, void* d_ws, size_t ws_size,
                              hipStream_t stream) {
  const float* x  = (const float*)d_in[0];
  const float* wq = (const float*)d_in[1];
  const float* bq = (const float*)d_in[2];
  const float* wk = (const float*)d_in[3];
  const float* bk = (const float*)d_in[4];
  const float* wv = (const float*)d_in[5];
  const float* bv = (const float*)d_in[6];
  const float* wo = (const float*)d_in[7];
  const float* bo = (const float*)d_in[8];
  const float* aq = (const float*)d_in[9];
  const float* uq = (const float*)d_in[10];
  const float* ak = (const float*)d_in[11];
  const float* uk = (const float*)d_in[12];
  const float* av = (const float*)d_in[13];
  const float* uv = (const float*)d_in[14];

  char* ws = (char*)d_ws;
  u16* xb       = (u16*)(ws);                      // 16 MB [0,16M)  (dead after QKV GEMM)
  u16* attn_o   = (u16*)(ws);                      // 16 MB (reuse)
  u16* qkv      = (u16*)(ws + (16u << 20));        // 32 MB [16M,48M)  Q,K stride 2048
  u16* vT       = (u16*)(ws + (48u << 20));        // 16 MB [48M,64M)  [b][h][d][s]
  u16* weffT    = (u16*)(ws + (64u << 20));        // 8 MB  [64M,72M)
  float* biasq  = (float*)(ws + (72u << 20));      // 12 KB

  prep_all_kernel<<<dim3(12300), dim3(256), 0, stream>>>(
      x, xb, wq, wk, wv, wo, aq, ak, av, uq, uk, uv, weffT, bq, bk, bv, biasq);
  gemm_tt<1><<<dim3(24, 64), dim3(256), 0, stream>>>(weffT, xb, (void*)qkv, vT, biasq, 2048, 1024);
  attn_kernel<<<dim3(16, 16, 4), dim3(256), 0, stream>>>(qkv, vT, attn_o);
  gemm_tt<0><<<dim3(8, 64), dim3(256), 0, stream>>>(weffT + 3u * 1048576u, attn_o, d_out, nullptr, bo, 1024, 1024);
}

// Round 6
// 298.005 us; speedup vs baseline: 1.0557x; 1.0557x over previous
//
#include <hip/hip_runtime.h>
#include <stdint.h>

typedef unsigned short u16;
typedef unsigned int u32;
typedef __bf16 bf16x8 __attribute__((ext_vector_type(8)));
typedef __bf16 bf16x4 __attribute__((ext_vector_type(4)));
typedef float f32x4 __attribute__((ext_vector_type(4)));
typedef float f32x16 __attribute__((ext_vector_type(16)));
typedef u32 u32x4 __attribute__((ext_vector_type(4)));

#define SEQ 2048
#define QSCALE 0.1803368801111137f  // log2(e)/8, folded into W_q_eff

__device__ __forceinline__ float fast_exp2(float x) { return __builtin_amdgcn_exp2f(x); }

// async 16B global->LDS copy (wave-uniform LDS base + lane*16)
__device__ __forceinline__ void async16(const void* g, void* l) {
  __builtin_amdgcn_global_load_lds((const __attribute__((address_space(1))) void*)g,
                                   (__attribute__((address_space(3))) void*)l, 16, 0, 0);
}

__device__ __forceinline__ u32 pkbf(float a, float b) {
  u16 xa = __builtin_bit_cast(u16, (__bf16)a);
  u16 xb = __builtin_bit_cast(u16, (__bf16)b);
  return (u32)xa | ((u32)xb << 16);
}

// ---------------- fused prep kernel ----------------
// blocks [0,8192): x fp32->bf16; [8192,12288): W_eff^T build; [12288,12300): bias.

__global__ void prep_all_kernel(const float* __restrict__ x, u16* __restrict__ xb,
                                const float* __restrict__ wq, const float* __restrict__ wk,
                                const float* __restrict__ wv, const float* __restrict__ wo,
                                const float* __restrict__ aq, const float* __restrict__ ak,
                                const float* __restrict__ av,
                                const float* __restrict__ uq, const float* __restrict__ uk,
                                const float* __restrict__ uv,
                                u16* __restrict__ weffT,
                                const float* __restrict__ bq, const float* __restrict__ bk,
                                const float* __restrict__ bv, float* __restrict__ bias_qkv) {
  __shared__ float wt[32][33];
  __shared__ float at[32][8];
  __shared__ float ut[8][33];
  const int bid = blockIdx.x;
  const int t = threadIdx.x;
  if (bid < 8192) {
    int i = (bid * 256 + t) * 4;
    float4 v = *(const float4*)(x + i);
    bf16x4 o;
    o[0] = (__bf16)v.x; o[1] = (__bf16)v.y; o[2] = (__bf16)v.z; o[3] = (__bf16)v.w;
    *(bf16x4*)(xb + i) = o;
  } else if (bid < 12288) {
    const int p = (bid - 8192) >> 10, bx = (bid - 8192) & 1023;
    const int tn0 = (bx & 31) * 32, tk0 = (bx >> 5) * 32;
    const float* w = (p == 0) ? wq : (p == 1) ? wk : (p == 2) ? wv : wo;
    const float* a = (p == 0) ? aq : (p == 1) ? ak : av;
    const float* u = (p == 0) ? uq : (p == 1) ? uk : uv;
    {
      int tk = t >> 3, tn4 = (t & 7) * 4;
      float4 v = *(const float4*)(w + (tk0 + tk) * 1024 + tn0 + tn4);
      wt[tk][tn4] = v.x; wt[tk][tn4 + 1] = v.y; wt[tk][tn4 + 2] = v.z; wt[tk][tn4 + 3] = v.w;
    }
    if (p < 3) {
      at[t >> 3][t & 7] = a[(tk0 + (t >> 3)) * 8 + (t & 7)];
      ut[t >> 5][t & 31] = u[(t >> 5) * 1024 + tn0 + (t & 31)];
    }
    __syncthreads();
    const int tn = t >> 3, tk4 = (t & 7) * 4;
    bf16x4 o;
#pragma unroll
    for (int jj = 0; jj < 4; ++jj) {
      int k = tk4 + jj;
      float val = wt[k][tn];
      if (p < 3) {
        float acc = 0.f;
#pragma unroll
        for (int r = 0; r < 8; ++r) acc += at[k][r] * ut[r][tn];
        val += 2.0f * acc;
      }
      if (p == 0) val *= QSCALE;
      o[jj] = (__bf16)val;
    }
    *(bf16x4*)(weffT + p * 1048576 + (tn0 + tn) * 1024 + tk0 + tk4) = o;
  } else {
    int i = (bid - 12288) * 256 + t;
    bias_qkv[i] = (i < 1024) ? bq[i] * QSCALE : (i < 2048) ? bk[i - 1024] : bv[i - 2048];
  }
}

// ---------------- GEMM: OUT[v][u] = dot(U[u], V[v]) + bias[u] ----------------
// Block 128(u) x 128(v), BK=32, 4 waves 2x2, wave tile 64x64 (4x4 MFMAs).
// MODE 0: fp32 dense store (stride NU). MODE 1: u<2048 -> bf16 qkv (stride 2048);
//         u>=2048 -> V^T scatter into vT[b][h][d][s] (L2 merges to full lines).

template <int MODE>
__global__ __launch_bounds__(256, 2)
void gemm_tt(const u16* __restrict__ U, const u16* __restrict__ V, void* __restrict__ OUT,
             u16* __restrict__ vT, const float* __restrict__ bias, const int NU, const int K) {
  __shared__ __align__(16) char smU[8192];
  __shared__ __align__(16) char smV[8192];
  const int t = threadIdx.x;
  const int lane = t & 63, ln = lane & 15, g = lane >> 4, w = t >> 6;
  const int u0 = blockIdx.x * 128, v0 = blockIdx.y * 128;
  const int wu = (w & 1) * 64, wv = (w >> 1) * 64;
  f32x4 acc[4][4] = {};
  for (int k0 = 0; k0 < K; k0 += 32) {
    __syncthreads();
#pragma unroll
    for (int half = 0; half < 2; ++half) {
      int p = half * 256 + t;
      int s = p >> 2, cp = p & 3;
      int c = cp ^ (s & 3);
      int ldsoff = (half * 256 + (t & 192)) * 16;
      async16(U + (u0 + s) * K + k0 + c * 8, smU + ldsoff);
      async16(V + (v0 + s) * K + k0 + c * 8, smV + ldsoff);
    }
    __syncthreads();
    bf16x8 af[4], bf[4];
#pragma unroll
    for (int mt = 0; mt < 4; ++mt)
      af[mt] = *(const bf16x8*)(smU + (wu + mt * 16 + ln) * 64 + ((g ^ (ln & 3)) * 16));
#pragma unroll
    for (int nt = 0; nt < 4; ++nt)
      bf[nt] = *(const bf16x8*)(smV + (wv + nt * 16 + ln) * 64 + ((g ^ (ln & 3)) * 16));
#pragma unroll
    for (int mt = 0; mt < 4; ++mt)
#pragma unroll
      for (int nt = 0; nt < 4; ++nt)
        acc[mt][nt] = __builtin_amdgcn_mfma_f32_16x16x32_bf16(af[mt], bf[nt], acc[mt][nt], 0, 0, 0);
  }
  const bool isV = (MODE == 1) && (u0 + wu >= 2048);  // wave-uniform
#pragma unroll
  for (int mt = 0; mt < 4; ++mt) {
    const int u = u0 + wu + mt * 16 + g * 4;
    const float4 bs = *(const float4*)(bias + u);
#pragma unroll
    for (int nt = 0; nt < 4; ++nt) {
      const int v = v0 + wv + nt * 16 + ln;
      f32x4 a = acc[mt][nt];
      a[0] += bs.x; a[1] += bs.y; a[2] += bs.z; a[3] += bs.w;
      if (MODE == 0) {
        *(float4*)((float*)OUT + (size_t)v * NU + u) = make_float4(a[0], a[1], a[2], a[3]);
      } else if (!isV) {
        bf16x4 o;
        o[0] = (__bf16)a[0]; o[1] = (__bf16)a[1]; o[2] = (__bf16)a[2]; o[3] = (__bf16)a[3];
        *(bf16x4*)((u16*)OUT + (size_t)v * 2048 + u) = o;
      } else {
        const int uu = u - 2048;
        const int hh = uu >> 6, dd = uu & 63;
        const int bb = v >> 11, ss = v & 2047;
        u16* dst = vT + ((size_t)((bb * 16 + hh) * 64 + dd)) * 2048 + ss;
#pragma unroll
        for (int r = 0; r < 4; ++r)
          *(__bf16*)(dst + (size_t)r * 2048) = (__bf16)a[r];
      }
    }
  }
}

// ---------------- flash attention v6 ----------------
// Block = (h, qt, b): 256 q, 4 waves x 64 q (2 n-tiles sharing all K/V frags).
// 32x32x16 MFMAs. Fixed-max softmax: P = exp2(raw S) (log2e/8 in W_q).
// Free P->B transpose via K-row bit2<->3 permutation at staging (v5 trick).
// l on MFMA pipe via ones A-fragment. DOUBLE-BUFFERED staging: prefetch kt+1
// issued before compute of kt; ONE barrier per kt (vmcnt drain overlaps compute).
// LDS: smK 2x16KB + smVt 2x16KB = 64KB -> 2 blocks/CU (grid 512 = exactly 2/CU).

__global__ __launch_bounds__(256, 2)
void attn_kernel(const u16* __restrict__ qkv, const u16* __restrict__ vT,
                 u16* __restrict__ attn_o) {
  __shared__ __align__(16) char smK[32768];   // [2 buf][128 rows][128B swz]
  __shared__ __align__(16) char smVt[32768];  // [2 buf][64 d][256B swz]
  const int t = threadIdx.x;
  const int lane = t & 63, q32 = lane & 31, hf = lane >> 5, w = t >> 6;
  const int hd = blockIdx.x, qt = blockIdx.y, b = blockIdx.z;
  const int q0 = qt * 256;
  const size_t base_b = (size_t)b * SEQ * 2048;
  const u16* qbase = qkv + base_b + hd * 64;
  const u16* kbase0 = qkv + base_b + 1024 + hd * 64;
  const u16* vbase0 = vT + ((size_t)(b * 16 + hd) * 64) * 2048;

  // Q B-frags (32x32x16): (ks, nt): q = q0 + w*64 + nt*32 + q32, k = ks*16 + hf*8
  bf16x8 qf[4][2];
#pragma unroll
  for (int ks = 0; ks < 4; ++ks)
#pragma unroll
    for (int nt = 0; nt < 2; ++nt)
      qf[ks][nt] = *(const bf16x8*)(qbase + (size_t)(q0 + w * 64 + nt * 32 + q32) * 2048 +
                                    ks * 16 + hf * 8);

  // ones A-fragment: tile row m=0 holds 1.0 across all k -> C row 0 = column sums
  bf16x8 ones_frag;
  {
    u32 o2 = (q32 == 0) ? 0x3F803F80u : 0u;
    u32x4 ow = {o2, o2, o2, o2};
    ones_frag = __builtin_bit_cast(bf16x8, ow);
  }

  // staging addresses (swizzled global source; K rows bit2<->3 permuted)
  const u16* srcK[4];
  const u16* srcV[4];
  char* dstK[4];
  char* dstV[4];
#pragma unroll
  for (int i = 0; i < 4; ++i) {
    int p = i * 256 + t;
    {
      int row = p >> 3, cp = p & 7;
      int rowp = (row & ~12) | ((row & 4) << 1) | ((row & 8) >> 1);  // swap bits 2,3
      int c = cp ^ (row & 7);
      srcK[i] = kbase0 + (size_t)rowp * 2048 + c * 8;
      dstK[i] = smK + (i * 256 + (t & 192)) * 16;
    }
    {
      int d = p >> 4, cp = p & 15;
      int key = (d & 15) ^ (d >> 3);
      int c = (cp ^ key) & 15;
      srcV[i] = vbase0 + (size_t)d * 2048 + c * 8;
      dstV[i] = smVt + (i * 256 + (t & 192)) * 16;
    }
  }

  // prologue: stage kt=0 into buffer 0
#pragma unroll
  for (int i = 0; i < 4; ++i) {
    async16(srcK[i], dstK[i]);
    srcK[i] += 128 * 2048;
  }
#pragma unroll
  for (int i = 0; i < 4; ++i) {
    async16(srcV[i], dstV[i]);
    srcV[i] += 128;
  }
  __syncthreads();

  f32x16 accO[2][2] = {};
  f32x16 acc_l[2] = {};

  for (int kt = 0; kt < 16; ++kt) {
    const int cur = kt & 1, nxt = cur ^ 1;
    // prefetch kt+1 into the other buffer (overlaps with compute below)
    if (kt < 15) {
#pragma unroll
      for (int i = 0; i < 4; ++i) {
        async16(srcK[i], dstK[i] + nxt * 16384);
        srcK[i] += 128 * 2048;
      }
#pragma unroll
      for (int i = 0; i < 4; ++i) {
        async16(srcV[i], dstV[i] + nxt * 16384);
        srcV[i] += 128;
      }
    }
    const char* kbuf = smK + cur * 16384;
    const char* vbuf = smVt + cur * 16384;

#pragma unroll
    for (int c = 0; c < 4; ++c) {
      // S^T for this 32-s' chunk (permuted rows), both n-tiles share K frags
      f32x16 stc[2] = {};
#pragma unroll
      for (int ks = 0; ks < 4; ++ks) {
        int row = c * 32 + q32;
        bf16x8 kfr = *(const bf16x8*)(kbuf + row * 128 + (((2 * ks + hf) ^ (row & 7)) * 16));
        stc[0] = __builtin_amdgcn_mfma_f32_32x32x16_bf16(kfr, qf[ks][0], stc[0], 0, 0, 0);
        stc[1] = __builtin_amdgcn_mfma_f32_32x32x16_bf16(kfr, qf[ks][1], stc[1], 0, 0, 0);
      }
      // exp2 -> pfrag (already B-operand order) -> l-MFMA + PV (V frags shared)
#pragma unroll
      for (int kh = 0; kh < 2; ++kh) {
        bf16x8 pfrag[2];
#pragma unroll
        for (int nt = 0; nt < 2; ++nt) {
          float e[8];
#pragma unroll
          for (int j = 0; j < 8; ++j) e[j] = fast_exp2(stc[nt][8 * kh + j]);
          u32x4 bw;
          bw[0] = pkbf(e[0], e[1]);
          bw[1] = pkbf(e[2], e[3]);
          bw[2] = pkbf(e[4], e[5]);
          bw[3] = pkbf(e[6], e[7]);
          pfrag[nt] = __builtin_bit_cast(bf16x8, bw);
          acc_l[nt] = __builtin_amdgcn_mfma_f32_32x32x16_bf16(ones_frag, pfrag[nt], acc_l[nt], 0, 0, 0);
        }
#pragma unroll
        for (int mt = 0; mt < 2; ++mt) {
          int row = mt * 32 + q32;
          int key = (row & 15) ^ (row >> 3);
          bf16x8 vfr = *(const bf16x8*)(vbuf + row * 256 +
                                        (((4 * c + 2 * kh + hf) ^ key) & 15) * 16);
          accO[mt][0] = __builtin_amdgcn_mfma_f32_32x32x16_bf16(vfr, pfrag[0], accO[mt][0], 0, 0, 0);
          accO[mt][1] = __builtin_amdgcn_mfma_f32_32x32x16_bf16(vfr, pfrag[1], accO[mt][1], 0, 0, 0);
        }
      }
    }
    if (kt < 15) __syncthreads();  // publishes prefetched buffer, retires cur readers
  }

  // epilogue: l[q] in acc_l[nt] reg 0, half-0 lane q; d quads reg-contiguous
#pragma unroll
  for (int nt = 0; nt < 2; ++nt) {
    float lv = __shfl(acc_l[nt][0], q32);
    float il = 1.0f / lv;
    const int s = q0 + w * 64 + nt * 32 + q32;
#pragma unroll
    for (int mt = 0; mt < 2; ++mt)
#pragma unroll
      for (int qd = 0; qd < 4; ++qd) {
        int d0 = 32 * mt + 8 * qd + 4 * hf;
        bf16x4 o;
#pragma unroll
        for (int r = 0; r < 4; ++r) o[r] = (__bf16)(accO[mt][nt][4 * qd + r] * il);
        *(bf16x4*)(attn_o + (size_t)(b * SEQ + s) * 1024 + hd * 64 + d0) = o;
      }
  }
}

// ---------------- launcher ----------------

extern "C" void kernel_launch(void* const* d_in, const int* in_sizes, int n_in,
                              void* d_out, int out_size, void* d_ws, size_t ws_size,
                              hipStream_t stream) {
  const float* x  = (const float*)d_in[0];
  const float* wq = (const float*)d_in[1];
  const float* bq = (const float*)d_in[2];
  const float* wk = (const float*)d_in[3];
  const float* bk = (const float*)d_in[4];
  const float* wv = (const float*)d_in[5];
  const float* bv = (const float*)d_in[6];
  const float* wo = (const float*)d_in[7];
  const float* bo = (const float*)d_in[8];
  const float* aq = (const float*)d_in[9];
  const float* uq = (const float*)d_in[10];
  const float* ak = (const float*)d_in[11];
  const float* uk = (const float*)d_in[12];
  const float* av = (const float*)d_in[13];
  const float* uv = (const float*)d_in[14];

  char* ws = (char*)d_ws;
  u16* xb       = (u16*)(ws);                      // 16 MB [0,16M)  (dead after QKV GEMM)
  u16* attn_o   = (u16*)(ws);                      // 16 MB (reuse)
  u16* qkv      = (u16*)(ws + (16u << 20));        // 32 MB [16M,48M)  Q,K stride 2048
  u16* vT       = (u16*)(ws + (48u << 20));        // 16 MB [48M,64M)  [b][h][d][s]
  u16* weffT    = (u16*)(ws + (64u << 20));        // 8 MB  [64M,72M)
  float* biasq  = (float*)(ws + (72u << 20));      // 12 KB

  prep_all_kernel<<<dim3(12300), dim3(256), 0, stream>>>(
      x, xb, wq, wk, wv, wo, aq, ak, av, uq, uk, uv, weffT, bq, bk, bv, biasq);
  gemm_tt<1><<<dim3(24, 64), dim3(256), 0, stream>>>(weffT, xb, (void*)qkv, vT, biasq, 2048, 1024);
  attn_kernel<<<dim3(16, 8, 4), dim3(256), 0, stream>>>(qkv, vT, attn_o);
  gemm_tt<0><<<dim3(8, 64), dim3(256), 0, stream>>>(weffT + 3u * 1048576u, attn_o, d_out, nullptr, bo, 1024, 1024);
}